// Round 1
// baseline (3608.978 us; speedup 1.0000x reference)
//
#include <hip/hip_runtime.h>

#define NB   16
#define NC   64
#define NPTS 65536
#define RES  32
#define R3   32768   // 32^3

// ---------------- K1: per-batch coordinate mean ----------------
__global__ void mean_kernel(const float* __restrict__ coords, float* __restrict__ mean) {
    int b = blockIdx.x;
    const float* cb = coords + (size_t)b * 3 * NPTS;
    float s0 = 0.f, s1 = 0.f, s2 = 0.f;
    for (int n = threadIdx.x; n < NPTS; n += blockDim.x) {
        s0 += cb[n];
        s1 += cb[NPTS + n];
        s2 += cb[2 * NPTS + n];
    }
    __shared__ float red[256];
    float vals[3] = {s0, s1, s2};
    for (int d = 0; d < 3; ++d) {
        red[threadIdx.x] = vals[d];
        __syncthreads();
        for (int off = 128; off > 0; off >>= 1) {
            if (threadIdx.x < off) red[threadIdx.x] += red[threadIdx.x + off];
            __syncthreads();
        }
        if (threadIdx.x == 0) mean[b * 3 + d] = red[0] * (1.0f / NPTS);
        __syncthreads();
    }
}

// ---------------- K2: per-batch max L2 norm of centered coords ----------------
__global__ void maxnorm_kernel(const float* __restrict__ coords,
                               const float* __restrict__ mean,
                               float* __restrict__ maxn) {
    int b = blockIdx.x;
    const float* cb = coords + (size_t)b * 3 * NPTS;
    float m0 = mean[b * 3 + 0], m1 = mean[b * 3 + 1], m2 = mean[b * 3 + 2];
    float mx = 0.f;
    for (int n = threadIdx.x; n < NPTS; n += blockDim.x) {
        float x = cb[n] - m0;
        float y = cb[NPTS + n] - m1;
        float z = cb[2 * NPTS + n] - m2;
        mx = fmaxf(mx, sqrtf(x * x + y * y + z * z));
    }
    __shared__ float red[256];
    red[threadIdx.x] = mx;
    __syncthreads();
    for (int off = 128; off > 0; off >>= 1) {
        if (threadIdx.x < off) red[threadIdx.x] = fmaxf(red[threadIdx.x], red[threadIdx.x + off]);
        __syncthreads();
    }
    if (threadIdx.x == 0) maxn[b] = red[0];
}

// ---------------- K3: normalize coords (2nd output) + scatter-add features ----------------
__global__ void scatter_kernel(const float* __restrict__ features,
                               const float* __restrict__ coords,
                               const float* __restrict__ mean,
                               const float* __restrict__ maxn,
                               float* __restrict__ grid,     // [B, C, R3] sums (pre-zeroed)
                               float* __restrict__ ncout,    // [B, 3, N]
                               float* __restrict__ cnt) {    // [B, R3] (pre-zeroed)
    int t = blockIdx.x * blockDim.x + threadIdx.x;   // 0 .. B*NPTS
    int b = t >> 16;            // NPTS = 2^16
    int n = t & (NPTS - 1);
    const float* cb = coords + (size_t)b * 3 * NPTS;
    float m2 = maxn[b] * 2.0f;  // EPS = 0
    float ncx = (cb[n]            - mean[b * 3 + 0]) / m2 + 0.5f;
    float ncy = (cb[NPTS + n]     - mean[b * 3 + 1]) / m2 + 0.5f;
    float ncz = (cb[2 * NPTS + n] - mean[b * 3 + 2]) / m2 + 0.5f;
    float sx = fminf(fmaxf(ncx * (float)RES, 0.f), (float)(RES - 1));
    float sy = fminf(fmaxf(ncy * (float)RES, 0.f), (float)(RES - 1));
    float sz = fminf(fmaxf(ncz * (float)RES, 0.f), (float)(RES - 1));
    float* nb = ncout + (size_t)b * 3 * NPTS;
    nb[n]            = sx;
    nb[NPTS + n]     = sy;
    nb[2 * NPTS + n] = sz;
    int vx = (int)rintf(sx);   // round-to-nearest-even, matches jnp.round
    int vy = (int)rintf(sy);
    int vz = (int)rintf(sz);
    int v = (vx << 10) + (vy << 5) + vz;
    atomicAdd(&cnt[((size_t)b << 15) + v], 1.0f);
    const float* fb = features + ((size_t)b << 22);  // b * C * NPTS
    float* gb = grid + ((size_t)b << 21);            // b * C * R3
#pragma unroll 8
    for (int c = 0; c < NC; ++c) {
        atomicAdd(&gb[((size_t)c << 15) + v], fb[((size_t)c << 16) + n]);
    }
}

// ---------------- K4: divide sums by counts in place ----------------
__global__ void finalize_kernel(float* __restrict__ grid, const float* __restrict__ cnt) {
    size_t i = (size_t)blockIdx.x * blockDim.x + threadIdx.x;  // 0 .. B*C*R3
    int v  = (int)(i & (R3 - 1));
    int bc = (int)(i >> 15);
    int b  = bc >> 6;  // / NC
    float ct = cnt[((size_t)b << 15) + v];
    grid[i] = grid[i] / fmaxf(ct, 1.0f);
}

extern "C" void kernel_launch(void* const* d_in, const int* in_sizes, int n_in,
                              void* d_out, int out_size, void* d_ws, size_t ws_size,
                              hipStream_t stream) {
    const float* features = (const float*)d_in[0];  // [16, 64, 65536]
    const float* coords   = (const float*)d_in[1];  // [16, 3, 65536]

    float* grid  = (float*)d_out;                       // [16, 64, 32768]
    float* ncout = grid + (size_t)NB * NC * R3;         // [16, 3, 65536]

    float* cnt  = (float*)d_ws;                         // [16, 32768]
    float* mean = cnt + (size_t)NB * R3;                // [16, 3]
    float* maxn = mean + NB * 3;                        // [16]

    // zero the accumulators (harness poisons d_out/d_ws with 0xAA each call)
    hipMemsetAsync(d_out, 0, (size_t)NB * NC * R3 * sizeof(float), stream);
    hipMemsetAsync(d_ws, 0, (size_t)NB * R3 * sizeof(float), stream);

    mean_kernel<<<NB, 256, 0, stream>>>(coords, mean);
    maxnorm_kernel<<<NB, 256, 0, stream>>>(coords, mean, maxn);
    scatter_kernel<<<(NB * NPTS) / 256, 256, 0, stream>>>(features, coords, mean, maxn,
                                                          grid, ncout, cnt);
    finalize_kernel<<<((size_t)NB * NC * R3) / 256, 256, 0, stream>>>(grid, cnt);
}

// Round 2
// 1931.391 us; speedup vs baseline: 1.8686x; 1.8686x over previous
//
#include <hip/hip_runtime.h>

#define NB   16
#define NC   64
#define NPTS 65536
#define RES  32
#define R3   32768
#define PPB  2048   // points per block in reduction kernels (32 blocks/batch)

// ---------------- K1: partial sums for per-batch coord mean ----------------
__global__ void mean_partial(const float* __restrict__ coords, float* __restrict__ meanacc) {
    int bid = blockIdx.x;
    int b = bid >> 5, chunk = bid & 31;
    const float* cb = coords + (size_t)b * 3 * NPTS + chunk * PPB;
    float s0 = 0.f, s1 = 0.f, s2 = 0.f;
    for (int i = threadIdx.x; i < PPB; i += 256) {
        s0 += cb[i];
        s1 += cb[NPTS + i];
        s2 += cb[2 * NPTS + i];
    }
    for (int off = 32; off > 0; off >>= 1) {
        s0 += __shfl_down(s0, off);
        s1 += __shfl_down(s1, off);
        s2 += __shfl_down(s2, off);
    }
    if ((threadIdx.x & 63) == 0) {
        atomicAdd(&meanacc[b * 3 + 0], s0);
        atomicAdd(&meanacc[b * 3 + 1], s1);
        atomicAdd(&meanacc[b * 3 + 2], s2);
    }
}

// ---------------- K2: per-batch max L2 norm (atomicMax on int-reinterpreted float) ----------------
__global__ void maxnorm_partial(const float* __restrict__ coords,
                                const float* __restrict__ meanacc,
                                int* __restrict__ maxn) {
    int bid = blockIdx.x;
    int b = bid >> 5, chunk = bid & 31;
    const float* cb = coords + (size_t)b * 3 * NPTS + chunk * PPB;
    float m0 = meanacc[b * 3 + 0] * (1.0f / NPTS);
    float m1 = meanacc[b * 3 + 1] * (1.0f / NPTS);
    float m2 = meanacc[b * 3 + 2] * (1.0f / NPTS);
    float mx = 0.f;
    for (int i = threadIdx.x; i < PPB; i += 256) {
        float x = cb[i] - m0;
        float y = cb[NPTS + i] - m1;
        float z = cb[2 * NPTS + i] - m2;
        mx = fmaxf(mx, sqrtf(x * x + y * y + z * z));
    }
    for (int off = 32; off > 0; off >>= 1)
        mx = fmaxf(mx, __shfl_down(mx, off));
    if ((threadIdx.x & 63) == 0)
        atomicMax(&maxn[b], __float_as_int(mx));   // norms >= 0: int order == float order
}

// ---------------- K3: normalize coords (2nd output), voxel id, count histogram ----------------
__global__ void voxelize(const float* __restrict__ coords,
                         const float* __restrict__ meanacc,
                         const int* __restrict__ maxn,
                         float* __restrict__ ncout,
                         unsigned short* __restrict__ voxid,
                         unsigned int* __restrict__ cnt) {
    int t = blockIdx.x * 256 + threadIdx.x;
    int b = t >> 16, n = t & (NPTS - 1);
    const float* cb = coords + (size_t)b * 3 * NPTS;
    float m2 = __int_as_float(maxn[b]) * 2.0f;   // EPS = 0
    float c0 = meanacc[b * 3 + 0] * (1.0f / NPTS);
    float c1 = meanacc[b * 3 + 1] * (1.0f / NPTS);
    float c2 = meanacc[b * 3 + 2] * (1.0f / NPTS);
    float ncx = (cb[n]            - c0) / m2 + 0.5f;
    float ncy = (cb[NPTS + n]     - c1) / m2 + 0.5f;
    float ncz = (cb[2 * NPTS + n] - c2) / m2 + 0.5f;
    float sx = fminf(fmaxf(ncx * (float)RES, 0.f), (float)(RES - 1));
    float sy = fminf(fmaxf(ncy * (float)RES, 0.f), (float)(RES - 1));
    float sz = fminf(fmaxf(ncz * (float)RES, 0.f), (float)(RES - 1));
    float* nb = ncout + (size_t)b * 3 * NPTS;
    nb[n]            = sx;
    nb[NPTS + n]     = sy;
    nb[2 * NPTS + n] = sz;
    int v = (((int)rintf(sx)) << 10) + (((int)rintf(sy)) << 5) + (int)rintf(sz);
    voxid[t] = (unsigned short)v;
    atomicAdd(&cnt[((size_t)b << 15) + v], 1u);
}

// ---------------- K4: per-batch exclusive scan of counts -> offsets (+cursor copy) ----------------
__global__ void scan_kernel(const unsigned int* __restrict__ cnt,
                            unsigned int* __restrict__ off,
                            unsigned int* __restrict__ cur) {
    __shared__ unsigned int s[1024];
    int b = blockIdx.x, tid = threadIdx.x;
    const unsigned int* cb = cnt + ((size_t)b << 15);
    int base = tid * 32;
    unsigned int local[32];
    unsigned int sum = 0;
    for (int j = 0; j < 32; ++j) { local[j] = cb[base + j]; sum += local[j]; }
    s[tid] = sum;
    __syncthreads();
    for (int o = 1; o < 1024; o <<= 1) {
        unsigned int t2 = (tid >= o) ? s[tid - o] : 0u;
        __syncthreads();
        s[tid] += t2;
        __syncthreads();
    }
    unsigned int run = s[tid] - sum;   // exclusive base for this thread's chunk
    unsigned int* ob = off + ((size_t)b << 15);
    unsigned int* ub = cur + ((size_t)b << 15);
    for (int j = 0; j < 32; ++j) {
        ob[base + j] = run;
        ub[base + j] = run;
        run += local[j];
    }
}

// ---------------- K5: scatter point ids into voxel-sorted order ----------------
__global__ void scatter_ids(const unsigned short* __restrict__ voxid,
                            unsigned int* __restrict__ cur,
                            unsigned short* __restrict__ sorted) {
    int t = blockIdx.x * 256 + threadIdx.x;
    int b = t >> 16, n = t & (NPTS - 1);
    int v = voxid[t];
    unsigned int pos = atomicAdd(&cur[((size_t)b << 15) + v], 1u);
    sorted[((size_t)b << 16) + pos] = (unsigned short)n;
}

// ---------------- K6: gather + mean, coalesced grid write ----------------
__global__ void gather_kernel(const float* __restrict__ features,
                              const unsigned short* __restrict__ sorted,
                              const unsigned int* __restrict__ off,
                              const unsigned int* __restrict__ cnt,
                              float* __restrict__ grid) {
    int bid = blockIdx.x;                 // b*8192 + c*128 + chunk  (slice-major for L2 locality)
    int b = bid >> 13;
    int c = (bid >> 7) & 63;
    int chunk = bid & 127;
    int v = (chunk << 8) + threadIdx.x;
    size_t bv = ((size_t)b << 15) + v;
    unsigned int base = off[bv];
    unsigned int k = cnt[bv];
    const float* f = features + ((size_t)((b << 6) + c) << 16);   // [b][c][:] slice, 256 KB
    const unsigned short* sp = sorted + ((size_t)b << 16);
    float sum = 0.f;
    for (unsigned int i = 0; i < k; ++i)
        sum += f[sp[base + i]];
    grid[((size_t)((b << 6) + c) << 15) + v] = sum / fmaxf((float)k, 1.0f);
}

extern "C" void kernel_launch(void* const* d_in, const int* in_sizes, int n_in,
                              void* d_out, int out_size, void* d_ws, size_t ws_size,
                              hipStream_t stream) {
    const float* features = (const float*)d_in[0];  // [16, 64, 65536]
    const float* coords   = (const float*)d_in[1];  // [16, 3, 65536]

    float* grid  = (float*)d_out;                    // [16, 64, 32768]
    float* ncout = grid + (size_t)NB * NC * R3;      // [16, 3, 65536]

    // ws layout: meanacc[48] f32 | maxn[16] i32 | (pad to 256B) | cnt | off | cur | voxid | sorted
    float* meanacc = (float*)d_ws;
    int*   maxn    = (int*)(meanacc + 48);
    unsigned int*   cnt    = (unsigned int*)((char*)d_ws + 256);
    unsigned int*   off    = cnt + (size_t)NB * R3;
    unsigned int*   cur    = off + (size_t)NB * R3;
    unsigned short* voxid  = (unsigned short*)(cur + (size_t)NB * R3);
    unsigned short* sorted = voxid + (size_t)NB * NPTS;

    // zero meanacc, maxn, cnt (~2 MB); everything else is fully overwritten
    hipMemsetAsync(d_ws, 0, 256 + (size_t)NB * R3 * sizeof(unsigned int), stream);

    mean_partial  <<<NB * 32, 256, 0, stream>>>(coords, meanacc);
    maxnorm_partial<<<NB * 32, 256, 0, stream>>>(coords, meanacc, maxn);
    voxelize      <<<NB * NPTS / 256, 256, 0, stream>>>(coords, meanacc, maxn, ncout, voxid, cnt);
    scan_kernel   <<<NB, 1024, 0, stream>>>(cnt, off, cur);
    scatter_ids   <<<NB * NPTS / 256, 256, 0, stream>>>(voxid, cur, sorted);
    gather_kernel <<<NB * NC * (R3 / 256), 256, 0, stream>>>(features, sorted, off, cnt, grid);
}

// Round 3
// 1507.123 us; speedup vs baseline: 2.3946x; 1.2815x over previous
//
#include <hip/hip_runtime.h>

#define NB   16
#define NC   64
#define NPTS 65536
#define RES  32
#define R3   32768
#define PPB  2048   // points per block in reduction kernels (32 blocks/batch)

// ---------------- K1: partial sums for per-batch coord mean ----------------
__global__ void mean_partial(const float* __restrict__ coords, float* __restrict__ meanacc) {
    int bid = blockIdx.x;
    int b = bid >> 5, chunk = bid & 31;
    const float* cb = coords + (size_t)b * 3 * NPTS + chunk * PPB;
    float s0 = 0.f, s1 = 0.f, s2 = 0.f;
    for (int i = threadIdx.x; i < PPB; i += 256) {
        s0 += cb[i];
        s1 += cb[NPTS + i];
        s2 += cb[2 * NPTS + i];
    }
    for (int off = 32; off > 0; off >>= 1) {
        s0 += __shfl_down(s0, off);
        s1 += __shfl_down(s1, off);
        s2 += __shfl_down(s2, off);
    }
    if ((threadIdx.x & 63) == 0) {
        atomicAdd(&meanacc[b * 3 + 0], s0);
        atomicAdd(&meanacc[b * 3 + 1], s1);
        atomicAdd(&meanacc[b * 3 + 2], s2);
    }
}

// ---------------- K2: per-batch max L2 norm (atomicMax on int-reinterpreted float) ----------------
__global__ void maxnorm_partial(const float* __restrict__ coords,
                                const float* __restrict__ meanacc,
                                int* __restrict__ maxn) {
    int bid = blockIdx.x;
    int b = bid >> 5, chunk = bid & 31;
    const float* cb = coords + (size_t)b * 3 * NPTS + chunk * PPB;
    float m0 = meanacc[b * 3 + 0] * (1.0f / NPTS);
    float m1 = meanacc[b * 3 + 1] * (1.0f / NPTS);
    float m2 = meanacc[b * 3 + 2] * (1.0f / NPTS);
    float mx = 0.f;
    for (int i = threadIdx.x; i < PPB; i += 256) {
        float x = cb[i] - m0;
        float y = cb[NPTS + i] - m1;
        float z = cb[2 * NPTS + i] - m2;
        mx = fmaxf(mx, sqrtf(x * x + y * y + z * z));
    }
    for (int off = 32; off > 0; off >>= 1)
        mx = fmaxf(mx, __shfl_down(mx, off));
    if ((threadIdx.x & 63) == 0)
        atomicMax(&maxn[b], __float_as_int(mx));   // norms >= 0: int order == float order
}

// ---------------- K3: normalize coords (2nd output), voxel id, count histogram ----------------
__global__ void voxelize(const float* __restrict__ coords,
                         const float* __restrict__ meanacc,
                         const int* __restrict__ maxn,
                         float* __restrict__ ncout,
                         unsigned short* __restrict__ voxid,
                         unsigned int* __restrict__ cnt) {
    int t = blockIdx.x * 256 + threadIdx.x;
    int b = t >> 16, n = t & (NPTS - 1);
    const float* cb = coords + (size_t)b * 3 * NPTS;
    float m2 = __int_as_float(maxn[b]) * 2.0f;   // EPS = 0
    float c0 = meanacc[b * 3 + 0] * (1.0f / NPTS);
    float c1 = meanacc[b * 3 + 1] * (1.0f / NPTS);
    float c2 = meanacc[b * 3 + 2] * (1.0f / NPTS);
    float ncx = (cb[n]            - c0) / m2 + 0.5f;
    float ncy = (cb[NPTS + n]     - c1) / m2 + 0.5f;
    float ncz = (cb[2 * NPTS + n] - c2) / m2 + 0.5f;
    float sx = fminf(fmaxf(ncx * (float)RES, 0.f), (float)(RES - 1));
    float sy = fminf(fmaxf(ncy * (float)RES, 0.f), (float)(RES - 1));
    float sz = fminf(fmaxf(ncz * (float)RES, 0.f), (float)(RES - 1));
    float* nb = ncout + (size_t)b * 3 * NPTS;
    nb[n]            = sx;
    nb[NPTS + n]     = sy;
    nb[2 * NPTS + n] = sz;
    int v = (((int)rintf(sx)) << 10) + (((int)rintf(sy)) << 5) + (int)rintf(sz);
    voxid[t] = (unsigned short)v;
    atomicAdd(&cnt[((size_t)b << 15) + v], 1u);
}

// ---------------- K4: per-batch exclusive scan of counts -> offsets (+cursor copy) ----------------
__global__ void scan_kernel(const unsigned int* __restrict__ cnt,
                            unsigned int* __restrict__ off,
                            unsigned int* __restrict__ cur) {
    __shared__ unsigned int s[1024];
    int b = blockIdx.x, tid = threadIdx.x;
    const unsigned int* cb = cnt + ((size_t)b << 15);
    int base = tid * 32;
    unsigned int local[32];
    unsigned int sum = 0;
    for (int j = 0; j < 32; ++j) { local[j] = cb[base + j]; sum += local[j]; }
    s[tid] = sum;
    __syncthreads();
    for (int o = 1; o < 1024; o <<= 1) {
        unsigned int t2 = (tid >= o) ? s[tid - o] : 0u;
        __syncthreads();
        s[tid] += t2;
        __syncthreads();
    }
    unsigned int run = s[tid] - sum;   // exclusive base for this thread's chunk
    unsigned int* ob = off + ((size_t)b << 15);
    unsigned int* ub = cur + ((size_t)b << 15);
    for (int j = 0; j < 32; ++j) {
        ob[base + j] = run;
        ub[base + j] = run;
        run += local[j];
    }
}

// ---------------- K5: scatter point ids into voxel-sorted order ----------------
__global__ void scatter_ids(const unsigned short* __restrict__ voxid,
                            unsigned int* __restrict__ cur,
                            unsigned short* __restrict__ sorted) {
    int t = blockIdx.x * 256 + threadIdx.x;
    int b = t >> 16, n = t & (NPTS - 1);
    int v = voxid[t];
    unsigned int pos = atomicAdd(&cur[((size_t)b << 15) + v], 1u);
    sorted[((size_t)b << 16) + pos] = (unsigned short)n;
}

// ---------------- K6: gather + mean, XCD-pinned slices for L2 residency ----------------
// blockIdx decomposition: bid = ((slice>>3)*128 + chunk)*8 + (slice&7)
//   => all 128 chunk-blocks of a slice share bid%8 (same XCD under round-robin
//      dispatch), and are consecutive within that XCD (~2 slices = 512 KB in
//      flight per XCD's 4 MB L2) -> feature slice fetched from HBM once.
__global__ void gather_kernel(const float* __restrict__ features,
                              const unsigned short* __restrict__ sorted,
                              const unsigned int* __restrict__ off,
                              const unsigned int* __restrict__ cnt,
                              float* __restrict__ grid) {
    int bid = blockIdx.x;            // 1024 slices * 128 chunks = 131072 blocks
    int xcd = bid & 7;
    int g   = bid >> 3;
    int k_  = g & 127;               // chunk within slice
    int sg  = g >> 7;                // slice group
    int s   = (sg << 3) + xcd;       // slice = b*64 + c
    int b = s >> 6;
    int c = s & 63;
    int v = (k_ << 8) + threadIdx.x;
    size_t bv = ((size_t)b << 15) + v;
    unsigned int base = off[bv];
    unsigned int k = cnt[bv];
    const float* f = features + ((size_t)s << 16);                // [b][c][:] slice, 256 KB
    const unsigned short* sp = sorted + ((size_t)b << 16);
    float sum = 0.f;
    for (unsigned int i = 0; i < k; ++i)
        sum += f[sp[base + i]];
    grid[((size_t)s << 15) + v] = sum / fmaxf((float)k, 1.0f);
}

extern "C" void kernel_launch(void* const* d_in, const int* in_sizes, int n_in,
                              void* d_out, int out_size, void* d_ws, size_t ws_size,
                              hipStream_t stream) {
    const float* features = (const float*)d_in[0];  // [16, 64, 65536]
    const float* coords   = (const float*)d_in[1];  // [16, 3, 65536]

    float* grid  = (float*)d_out;                    // [16, 64, 32768]
    float* ncout = grid + (size_t)NB * NC * R3;      // [16, 3, 65536]

    // ws layout: meanacc[48] f32 | maxn[16] i32 | (pad to 256B) | cnt | off | cur | voxid | sorted
    float* meanacc = (float*)d_ws;
    int*   maxn    = (int*)(meanacc + 48);
    unsigned int*   cnt    = (unsigned int*)((char*)d_ws + 256);
    unsigned int*   off    = cnt + (size_t)NB * R3;
    unsigned int*   cur    = off + (size_t)NB * R3;
    unsigned short* voxid  = (unsigned short*)(cur + (size_t)NB * R3);
    unsigned short* sorted = voxid + (size_t)NB * NPTS;

    // zero meanacc, maxn, cnt (~2 MB); everything else is fully overwritten
    hipMemsetAsync(d_ws, 0, 256 + (size_t)NB * R3 * sizeof(unsigned int), stream);

    mean_partial  <<<NB * 32, 256, 0, stream>>>(coords, meanacc);
    maxnorm_partial<<<NB * 32, 256, 0, stream>>>(coords, meanacc, maxn);
    voxelize      <<<NB * NPTS / 256, 256, 0, stream>>>(coords, meanacc, maxn, ncout, voxid, cnt);
    scan_kernel   <<<NB, 1024, 0, stream>>>(cnt, off, cur);
    scatter_ids   <<<NB * NPTS / 256, 256, 0, stream>>>(voxid, cur, sorted);
    gather_kernel <<<NB * NC * (R3 / 256), 256, 0, stream>>>(features, sorted, off, cnt, grid);
}

// Round 4
// 1054.203 us; speedup vs baseline: 3.4234x; 1.4296x over previous
//
#include <hip/hip_runtime.h>

#define NB   16
#define NC   64
#define NPTS 65536
#define RES  32
#define R3   32768
#define PPB  2048   // points per block in reduction kernels (32 blocks/batch)

// ---------------- K1: partial sums for per-batch coord mean ----------------
__global__ void mean_partial(const float* __restrict__ coords, float* __restrict__ meanacc) {
    int bid = blockIdx.x;
    int b = bid >> 5, chunk = bid & 31;
    const float* cb = coords + (size_t)b * 3 * NPTS + chunk * PPB;
    float s0 = 0.f, s1 = 0.f, s2 = 0.f;
    for (int i = threadIdx.x; i < PPB; i += 256) {
        s0 += cb[i];
        s1 += cb[NPTS + i];
        s2 += cb[2 * NPTS + i];
    }
    for (int off = 32; off > 0; off >>= 1) {
        s0 += __shfl_down(s0, off);
        s1 += __shfl_down(s1, off);
        s2 += __shfl_down(s2, off);
    }
    if ((threadIdx.x & 63) == 0) {
        atomicAdd(&meanacc[b * 3 + 0], s0);
        atomicAdd(&meanacc[b * 3 + 1], s1);
        atomicAdd(&meanacc[b * 3 + 2], s2);
    }
}

// ---------------- K2: per-batch max L2 norm (atomicMax on int-reinterpreted float) ----------------
__global__ void maxnorm_partial(const float* __restrict__ coords,
                                const float* __restrict__ meanacc,
                                int* __restrict__ maxn) {
    int bid = blockIdx.x;
    int b = bid >> 5, chunk = bid & 31;
    const float* cb = coords + (size_t)b * 3 * NPTS + chunk * PPB;
    float m0 = meanacc[b * 3 + 0] * (1.0f / NPTS);
    float m1 = meanacc[b * 3 + 1] * (1.0f / NPTS);
    float m2 = meanacc[b * 3 + 2] * (1.0f / NPTS);
    float mx = 0.f;
    for (int i = threadIdx.x; i < PPB; i += 256) {
        float x = cb[i] - m0;
        float y = cb[NPTS + i] - m1;
        float z = cb[2 * NPTS + i] - m2;
        mx = fmaxf(mx, sqrtf(x * x + y * y + z * z));
    }
    for (int off = 32; off > 0; off >>= 1)
        mx = fmaxf(mx, __shfl_down(mx, off));
    if ((threadIdx.x & 63) == 0)
        atomicMax(&maxn[b], __float_as_int(mx));   // norms >= 0: int order == float order
}

// ---------------- K3: normalize coords (2nd output), voxel id, count histogram ----------------
__global__ void voxelize(const float* __restrict__ coords,
                         const float* __restrict__ meanacc,
                         const int* __restrict__ maxn,
                         float* __restrict__ ncout,
                         unsigned short* __restrict__ voxid,
                         unsigned int* __restrict__ cnt) {
    int t = blockIdx.x * 256 + threadIdx.x;
    int b = t >> 16, n = t & (NPTS - 1);
    const float* cb = coords + (size_t)b * 3 * NPTS;
    float m2 = __int_as_float(maxn[b]) * 2.0f;   // EPS = 0
    float c0 = meanacc[b * 3 + 0] * (1.0f / NPTS);
    float c1 = meanacc[b * 3 + 1] * (1.0f / NPTS);
    float c2 = meanacc[b * 3 + 2] * (1.0f / NPTS);
    float ncx = (cb[n]            - c0) / m2 + 0.5f;
    float ncy = (cb[NPTS + n]     - c1) / m2 + 0.5f;
    float ncz = (cb[2 * NPTS + n] - c2) / m2 + 0.5f;
    float sx = fminf(fmaxf(ncx * (float)RES, 0.f), (float)(RES - 1));
    float sy = fminf(fmaxf(ncy * (float)RES, 0.f), (float)(RES - 1));
    float sz = fminf(fmaxf(ncz * (float)RES, 0.f), (float)(RES - 1));
    float* nb = ncout + (size_t)b * 3 * NPTS;
    nb[n]            = sx;
    nb[NPTS + n]     = sy;
    nb[2 * NPTS + n] = sz;
    int v = (((int)rintf(sx)) << 10) + (((int)rintf(sy)) << 5) + (int)rintf(sz);
    voxid[t] = (unsigned short)v;
    atomicAdd(&cnt[((size_t)b << 15) + v], 1u);
}

// ---------------- K4: per-batch exclusive scan of counts -> offsets (+cursor copy) ----------------
__global__ void scan_kernel(const unsigned int* __restrict__ cnt,
                            unsigned int* __restrict__ off,
                            unsigned int* __restrict__ cur) {
    __shared__ unsigned int s[1024];
    int b = blockIdx.x, tid = threadIdx.x;
    const unsigned int* cb = cnt + ((size_t)b << 15);
    int base = tid * 32;
    unsigned int local[32];
    unsigned int sum = 0;
    for (int j = 0; j < 32; ++j) { local[j] = cb[base + j]; sum += local[j]; }
    s[tid] = sum;
    __syncthreads();
    for (int o = 1; o < 1024; o <<= 1) {
        unsigned int t2 = (tid >= o) ? s[tid - o] : 0u;
        __syncthreads();
        s[tid] += t2;
        __syncthreads();
    }
    unsigned int run = s[tid] - sum;   // exclusive base for this thread's chunk
    unsigned int* ob = off + ((size_t)b << 15);
    unsigned int* ub = cur + ((size_t)b << 15);
    for (int j = 0; j < 32; ++j) {
        ob[base + j] = run;
        ub[base + j] = run;
        run += local[j];
    }
}

// ============ PATH A (ws big enough): row-transpose into sorted order, then stream ============

// K5a: coalesced-read a 128-point x 64-ch tile, LDS-transpose, write each point's
// 64-ch row as one contiguous 256B store at its voxel-sorted slot.
__global__ void transpose_scatter(const float* __restrict__ features,
                                  const unsigned short* __restrict__ voxid,
                                  unsigned int* __restrict__ cur,
                                  float* __restrict__ sortedfeat) {
    __shared__ float lds[128 * 65];
    __shared__ unsigned int posArr[128];
    int bid = blockIdx.x;                  // 16 * 512 blocks
    int b = bid >> 9;
    int n0 = (bid & 511) << 7;             // 128 points per block
    int pt = threadIdx.x & 127;
    int half = threadIdx.x >> 7;           // 0/1 -> channels 0..31 / 32..63
    const float* fb = features + ((size_t)b << 22) + n0 + pt;
#pragma unroll
    for (int cc = 0; cc < 32; ++cc) {
        int c = (half << 5) + cc;
        lds[pt * 65 + c] = fb[(size_t)c << 16];   // coalesced 512B per (c)
    }
    if (threadIdx.x < 128) {
        int v = voxid[((size_t)b << 16) + n0 + threadIdx.x];
        posArr[threadIdx.x] = atomicAdd(&cur[((size_t)b << 15) + v], 1u);
    }
    __syncthreads();
    int w = threadIdx.x >> 6;              // 4 waves, 32 points each
    int lane = threadIdx.x & 63;
    for (int p = (w << 5); p < (w << 5) + 32; ++p) {
        unsigned int pos = posArr[p];
        sortedfeat[((size_t)((b << 16) + pos) << 6) + lane] = lds[p * 65 + lane];
    }
}

// K6a: per voxel (lane=channel) stream its contiguous rows, mean, LDS-transpose,
// coalesced grid write.
__global__ void gather_rows(const float* __restrict__ sortedfeat,
                            const unsigned int* __restrict__ off,
                            const unsigned int* __restrict__ cnt,
                            float* __restrict__ grid) {
    __shared__ float lds[64 * 65];
    int bid = blockIdx.x;                  // 16 * 512 blocks, 64 voxels each
    int b = bid >> 9;
    int vblk = (bid & 511) << 6;
    int w = threadIdx.x >> 6;              // wave
    int lane = threadIdx.x & 63;           // = channel in phase A, = voxel in phase B
    for (int j = 0; j < 16; ++j) {
        int l = (j << 2) + w;              // interleave voxels across waves (balance)
        int v = vblk + l;
        size_t bv = ((size_t)b << 15) + v;
        unsigned int base = off[bv];
        unsigned int k = cnt[bv];
        const float* row = sortedfeat + ((size_t)((b << 16) + base) << 6) + lane;
        float sum = 0.f;
        for (unsigned int i = 0; i < k; ++i)
            sum += row[(size_t)i << 6];    // contiguous 256B per iteration
        lds[l * 65 + lane] = sum / fmaxf((float)k, 1.0f);
    }
    __syncthreads();
    for (int cc = 0; cc < 16; ++cc) {
        int c = (w << 4) + cc;
        grid[((size_t)((b << 6) + c) << 15) + vblk + lane] = lds[lane * 65 + c];
    }
}

// ============ PATH B (fallback): sorted-index gather with 8-ch ILP ============

__global__ void scatter_ids(const unsigned short* __restrict__ voxid,
                            unsigned int* __restrict__ cur,
                            unsigned short* __restrict__ sorted) {
    int t = blockIdx.x * 256 + threadIdx.x;
    int b = t >> 16, n = t & (NPTS - 1);
    int v = voxid[t];
    unsigned int pos = atomicAdd(&cur[((size_t)b << 15) + v], 1u);
    sorted[((size_t)b << 16) + pos] = (unsigned short)n;
}

// 8 channels per thread: one index load amortized over 8 independent feature
// loads in flight; XCD-pinned so the 8-slice (2MB) window stays L2-resident.
__global__ void gather_cpt8(const float* __restrict__ features,
                            const unsigned short* __restrict__ sorted,
                            const unsigned int* __restrict__ off,
                            const unsigned int* __restrict__ cnt,
                            float* __restrict__ grid) {
    int bid = blockIdx.x;                  // 128 slicegroups * 128 chunks
    int xcd = bid & 7;
    int g_  = bid >> 3;
    int chunk = g_ & 127;
    int sgg = g_ >> 7;
    int sg = (sgg << 3) + xcd;             // b*8 + cgroup
    int b = sg >> 3;
    int c0 = (sg & 7) << 3;
    int v = (chunk << 8) + threadIdx.x;
    size_t bv = ((size_t)b << 15) + v;
    unsigned int base = off[bv];
    unsigned int k = cnt[bv];
    const unsigned short* sp = sorted + ((size_t)b << 16);
    const float* f = features + ((size_t)((b << 6) + c0) << 16);
    float s[8] = {0,0,0,0,0,0,0,0};
    for (unsigned int i = 0; i < k; ++i) {
        int idx = sp[base + i];
#pragma unroll
        for (int j = 0; j < 8; ++j)
            s[j] += f[((size_t)j << 16) + idx];
    }
    float inv = 1.0f / fmaxf((float)k, 1.0f);
#pragma unroll
    for (int j = 0; j < 8; ++j)
        grid[((size_t)((b << 6) + c0 + j) << 15) + v] = s[j] * inv;
}

extern "C" void kernel_launch(void* const* d_in, const int* in_sizes, int n_in,
                              void* d_out, int out_size, void* d_ws, size_t ws_size,
                              hipStream_t stream) {
    const float* features = (const float*)d_in[0];  // [16, 64, 65536]
    const float* coords   = (const float*)d_in[1];  // [16, 3, 65536]

    float* grid  = (float*)d_out;                    // [16, 64, 32768]
    float* ncout = grid + (size_t)NB * NC * R3;      // [16, 3, 65536]

    // ws: meanacc[48] | maxn[16] | pad->256B | cnt 2MB | off 2MB | cur 2MB |
    //     voxid 2MB(u16) | sorted 2MB(u16) | sortedfeat 268MB (path A only)
    char* base = (char*)d_ws;
    float* meanacc = (float*)base;
    int*   maxn    = (int*)(base + 192);
    unsigned int*   cnt    = (unsigned int*)(base + 256);
    unsigned int*   off    = cnt + (size_t)NB * R3;
    unsigned int*   cur    = off + (size_t)NB * R3;
    unsigned short* voxid  = (unsigned short*)(cur + (size_t)NB * R3);
    unsigned short* sorted = voxid + (size_t)NB * NPTS;
    const size_t sf_off = 256 + 3 * (size_t)NB * R3 * 4 + 2 * (size_t)NB * NPTS * 2;
    float* sortedfeat = (float*)(base + sf_off);
    const bool pathA = ws_size >= sf_off + (size_t)NB * NPTS * NC * sizeof(float);

    // zero meanacc/maxn/cnt (~2 MB); everything else fully overwritten
    hipMemsetAsync(d_ws, 0, 256 + (size_t)NB * R3 * sizeof(unsigned int), stream);

    mean_partial   <<<NB * 32, 256, 0, stream>>>(coords, meanacc);
    maxnorm_partial<<<NB * 32, 256, 0, stream>>>(coords, meanacc, maxn);
    voxelize       <<<NB * NPTS / 256, 256, 0, stream>>>(coords, meanacc, maxn, ncout, voxid, cnt);
    scan_kernel    <<<NB, 1024, 0, stream>>>(cnt, off, cur);
    if (pathA) {
        transpose_scatter<<<NB * (NPTS / 128), 256, 0, stream>>>(features, voxid, cur, sortedfeat);
        gather_rows      <<<NB * (R3 / 64), 256, 0, stream>>>(sortedfeat, off, cnt, grid);
    } else {
        scatter_ids<<<NB * NPTS / 256, 256, 0, stream>>>(voxid, cur, sorted);
        gather_cpt8<<<(NB * 8) * (R3 / 256), 256, 0, stream>>>(features, sorted, off, cnt, grid);
    }
}

// Round 5
// 974.835 us; speedup vs baseline: 3.7021x; 1.0814x over previous
//
#include <hip/hip_runtime.h>

#define NB   16
#define NC   64
#define NPTS 65536
#define RES  32
#define R3   32768
#define PPB  2048   // points per block in reduction kernels (32 blocks/batch)

// ---------------- K1: partial sums for per-batch coord mean ----------------
__global__ void mean_partial(const float* __restrict__ coords, float* __restrict__ meanacc) {
    int bid = blockIdx.x;
    int b = bid >> 5, chunk = bid & 31;
    const float* cb = coords + (size_t)b * 3 * NPTS + chunk * PPB;
    float s0 = 0.f, s1 = 0.f, s2 = 0.f;
    for (int i = threadIdx.x; i < PPB; i += 256) {
        s0 += cb[i];
        s1 += cb[NPTS + i];
        s2 += cb[2 * NPTS + i];
    }
    for (int off = 32; off > 0; off >>= 1) {
        s0 += __shfl_down(s0, off);
        s1 += __shfl_down(s1, off);
        s2 += __shfl_down(s2, off);
    }
    if ((threadIdx.x & 63) == 0) {
        atomicAdd(&meanacc[b * 3 + 0], s0);
        atomicAdd(&meanacc[b * 3 + 1], s1);
        atomicAdd(&meanacc[b * 3 + 2], s2);
    }
}

// ---------------- K2: per-batch max L2 norm (atomicMax on int-reinterpreted float) ----------------
__global__ void maxnorm_partial(const float* __restrict__ coords,
                                const float* __restrict__ meanacc,
                                int* __restrict__ maxn) {
    int bid = blockIdx.x;
    int b = bid >> 5, chunk = bid & 31;
    const float* cb = coords + (size_t)b * 3 * NPTS + chunk * PPB;
    float m0 = meanacc[b * 3 + 0] * (1.0f / NPTS);
    float m1 = meanacc[b * 3 + 1] * (1.0f / NPTS);
    float m2 = meanacc[b * 3 + 2] * (1.0f / NPTS);
    float mx = 0.f;
    for (int i = threadIdx.x; i < PPB; i += 256) {
        float x = cb[i] - m0;
        float y = cb[NPTS + i] - m1;
        float z = cb[2 * NPTS + i] - m2;
        mx = fmaxf(mx, sqrtf(x * x + y * y + z * z));
    }
    for (int off = 32; off > 0; off >>= 1)
        mx = fmaxf(mx, __shfl_down(mx, off));
    if ((threadIdx.x & 63) == 0)
        atomicMax(&maxn[b], __float_as_int(mx));   // norms >= 0: int order == float order
}

// ---------------- K3: normalize coords (2nd output), voxel id, count histogram ----------------
__global__ void voxelize(const float* __restrict__ coords,
                         const float* __restrict__ meanacc,
                         const int* __restrict__ maxn,
                         float* __restrict__ ncout,
                         unsigned short* __restrict__ voxid,
                         unsigned int* __restrict__ cnt) {
    int t = blockIdx.x * 256 + threadIdx.x;
    int b = t >> 16, n = t & (NPTS - 1);
    const float* cb = coords + (size_t)b * 3 * NPTS;
    float m2 = __int_as_float(maxn[b]) * 2.0f;   // EPS = 0
    float c0 = meanacc[b * 3 + 0] * (1.0f / NPTS);
    float c1 = meanacc[b * 3 + 1] * (1.0f / NPTS);
    float c2 = meanacc[b * 3 + 2] * (1.0f / NPTS);
    float ncx = (cb[n]            - c0) / m2 + 0.5f;
    float ncy = (cb[NPTS + n]     - c1) / m2 + 0.5f;
    float ncz = (cb[2 * NPTS + n] - c2) / m2 + 0.5f;
    float sx = fminf(fmaxf(ncx * (float)RES, 0.f), (float)(RES - 1));
    float sy = fminf(fmaxf(ncy * (float)RES, 0.f), (float)(RES - 1));
    float sz = fminf(fmaxf(ncz * (float)RES, 0.f), (float)(RES - 1));
    float* nb = ncout + (size_t)b * 3 * NPTS;
    nb[n]            = sx;
    nb[NPTS + n]     = sy;
    nb[2 * NPTS + n] = sz;
    int v = (((int)rintf(sx)) << 10) + (((int)rintf(sy)) << 5) + (int)rintf(sz);
    voxid[t] = (unsigned short)v;
    atomicAdd(&cnt[((size_t)b << 15) + v], 1u);
}

// ---------------- K4: per-batch exclusive scan of counts -> offsets (+cursor copy) ----------------
__global__ void scan_kernel(const unsigned int* __restrict__ cnt,
                            unsigned int* __restrict__ off,
                            unsigned int* __restrict__ cur) {
    __shared__ unsigned int s[1024];
    int b = blockIdx.x, tid = threadIdx.x;
    const unsigned int* cb = cnt + ((size_t)b << 15);
    int base = tid * 32;
    unsigned int local[32];
    unsigned int sum = 0;
    for (int j = 0; j < 32; ++j) { local[j] = cb[base + j]; sum += local[j]; }
    s[tid] = sum;
    __syncthreads();
    for (int o = 1; o < 1024; o <<= 1) {
        unsigned int t2 = (tid >= o) ? s[tid - o] : 0u;
        __syncthreads();
        s[tid] += t2;
        __syncthreads();
    }
    unsigned int run = s[tid] - sum;   // exclusive base for this thread's chunk
    unsigned int* ob = off + ((size_t)b << 15);
    unsigned int* ub = cur + ((size_t)b << 15);
    for (int j = 0; j < 32; ++j) {
        ob[base + j] = run;
        ub[base + j] = run;
        run += local[j];
    }
}

// ============ PATH A: transpose into voxel-sorted bf16 rows, then segmented reduce ============

// K5a: coalesced-read a 128-point x 64-ch tile, LDS-transpose, write each point's
// 64-ch row (bf16, 128B contiguous) at its voxel-sorted slot; also record the
// row's voxel id for the segmented reduction.
__global__ void transpose_scatter(const float* __restrict__ features,
                                  const unsigned short* __restrict__ voxid,
                                  unsigned int* __restrict__ cur,
                                  unsigned short* __restrict__ sortedfeat,  // bf16 rows
                                  unsigned short* __restrict__ sortedvox) {
    __shared__ float lds[128 * 65];
    __shared__ unsigned int posArr[128];
    int bid = blockIdx.x;                  // 16 * 512 blocks
    int b = bid >> 9;
    int n0 = (bid & 511) << 7;             // 128 points per block
    int pt = threadIdx.x & 127;
    int half = threadIdx.x >> 7;           // 0/1 -> channels 0..31 / 32..63
    const float* fb = features + ((size_t)b << 22) + n0 + pt;
#pragma unroll
    for (int cc = 0; cc < 32; ++cc) {
        int c = (half << 5) + cc;
        lds[pt * 65 + c] = fb[(size_t)c << 16];   // coalesced 512B per (c)
    }
    if (threadIdx.x < 128) {
        int v = voxid[((size_t)b << 16) + n0 + threadIdx.x];
        unsigned int pos = atomicAdd(&cur[((size_t)b << 15) + v], 1u);
        posArr[threadIdx.x] = pos;
        sortedvox[((size_t)b << 16) + pos] = (unsigned short)v;
    }
    __syncthreads();
    int w = threadIdx.x >> 6;              // 4 waves, 32 points each
    int lane = threadIdx.x & 63;
    for (int p = (w << 5); p < (w << 5) + 32; ++p) {
        unsigned int pos = posArr[p];
        float f = lds[p * 65 + lane];
        unsigned int x = __float_as_uint(f);
        unsigned short h = (unsigned short)((x + 0x7fffu + ((x >> 16) & 1u)) >> 16);  // RNE bf16
        sortedfeat[(((size_t)((b << 16) + pos)) << 6) + lane] = h;
    }
}

// K6a: segmented reduction over sorted rows. One wave per 128-row chunk
// (uniform work). lane = channel. Fully-contained segments -> exclusive
// non-atomic write of the mean; boundary segments -> atomicAdd sums + list.
__global__ void seg_reduce(const unsigned short* __restrict__ sf,    // bf16 rows
                           const unsigned short* __restrict__ svox,
                           const unsigned int* __restrict__ off,
                           const unsigned int* __restrict__ cnt,
                           float* __restrict__ grid,                 // pre-zeroed
                           unsigned int* __restrict__ blist,
                           unsigned int* __restrict__ bcount) {
    int wid = (blockIdx.x * 256 + threadIdx.x) >> 6;   // 8192 waves
    int lane = threadIdx.x & 63;
    int b = wid >> 9;                    // 512 chunks per batch
    unsigned int base = (unsigned int)((wid & 511) << 7);
    const unsigned short* sfb = sf + ((((size_t)b << 16) + base) << 6);
    const unsigned short* svb = svox + ((size_t)b << 16) + base;
    const unsigned int* offb = off + ((size_t)b << 15);
    const unsigned int* cntb = cnt + ((size_t)b << 15);
    float* gb = grid + ((size_t)b << 21);              // b * 64 * 32768
    float acc = 0.f;
    int vcur = svb[0];
    for (int i = 0; i < 128; ++i) {
        int v = svb[i];
        if (v != vcur) {                               // wave-uniform branch
            unsigned int o = offb[vcur];
            if (o >= base) {                           // started here, ended mid-chunk -> exclusive
                gb[((size_t)lane << 15) + vcur] = acc / (float)cntb[vcur];
            } else {                                   // continuation from previous chunk
                atomicAdd(&gb[((size_t)lane << 15) + vcur], acc);
            }
            acc = 0.f;
            vcur = v;
        }
        unsigned int u = sfb[(i << 6) + lane];
        acc += __uint_as_float(u << 16);               // bf16 -> f32
    }
    unsigned int o = offb[vcur], k = cntb[vcur];
    bool startsHere = (o >= base);
    bool endsHere   = (o + k <= base + 128u);
    if (startsHere && endsHere) {
        gb[((size_t)lane << 15) + vcur] = acc / (float)k;
    } else {
        atomicAdd(&gb[((size_t)lane << 15) + vcur], acc);
        if (startsHere && lane == 0) {                 // exactly one chunk owns the start
            unsigned int p = atomicAdd(bcount, 1u);
            blist[p] = ((unsigned int)b << 15) | (unsigned int)vcur;
        }
    }
}

// K7a: divide the boundary voxels (sums) by their counts.
__global__ void fix_boundary(const unsigned int* __restrict__ blist,
                             const unsigned int* __restrict__ bcount,
                             const unsigned int* __restrict__ cnt,
                             float* __restrict__ grid) {
    int w = (blockIdx.x * 256 + threadIdx.x) >> 6;     // 8192 waves max
    int lane = threadIdx.x & 63;
    if ((unsigned int)w >= *bcount) return;
    unsigned int e = blist[w];
    int b = e >> 15, v = e & (R3 - 1);
    float k = (float)cnt[((size_t)b << 15) + v];
    size_t idx = (((size_t)((b << 6) + lane)) << 15) + v;
    grid[idx] = grid[idx] / fmaxf(k, 1.0f);
}

// ============ PATH B (fallback, small ws): sorted-index gather with 8-ch ILP ============

__global__ void scatter_ids(const unsigned short* __restrict__ voxid,
                            unsigned int* __restrict__ cur,
                            unsigned short* __restrict__ sorted) {
    int t = blockIdx.x * 256 + threadIdx.x;
    int b = t >> 16, n = t & (NPTS - 1);
    int v = voxid[t];
    unsigned int pos = atomicAdd(&cur[((size_t)b << 15) + v], 1u);
    sorted[((size_t)b << 16) + pos] = (unsigned short)n;
}

__global__ void gather_cpt8(const float* __restrict__ features,
                            const unsigned short* __restrict__ sorted,
                            const unsigned int* __restrict__ off,
                            const unsigned int* __restrict__ cnt,
                            float* __restrict__ grid) {
    int bid = blockIdx.x;
    int xcd = bid & 7;
    int g_  = bid >> 3;
    int chunk = g_ & 127;
    int sgg = g_ >> 7;
    int sg = (sgg << 3) + xcd;
    int b = sg >> 3;
    int c0 = (sg & 7) << 3;
    int v = (chunk << 8) + threadIdx.x;
    size_t bv = ((size_t)b << 15) + v;
    unsigned int base = off[bv];
    unsigned int k = cnt[bv];
    const unsigned short* sp = sorted + ((size_t)b << 16);
    const float* f = features + ((size_t)((b << 6) + c0) << 16);
    float s[8] = {0,0,0,0,0,0,0,0};
    for (unsigned int i = 0; i < k; ++i) {
        int idx = sp[base + i];
#pragma unroll
        for (int j = 0; j < 8; ++j)
            s[j] += f[((size_t)j << 16) + idx];
    }
    float inv = 1.0f / fmaxf((float)k, 1.0f);
#pragma unroll
    for (int j = 0; j < 8; ++j)
        grid[((size_t)((b << 6) + c0 + j) << 15) + v] = s[j] * inv;
}

extern "C" void kernel_launch(void* const* d_in, const int* in_sizes, int n_in,
                              void* d_out, int out_size, void* d_ws, size_t ws_size,
                              hipStream_t stream) {
    const float* features = (const float*)d_in[0];  // [16, 64, 65536]
    const float* coords   = (const float*)d_in[1];  // [16, 3, 65536]

    float* grid  = (float*)d_out;                    // [16, 64, 32768]
    float* ncout = grid + (size_t)NB * NC * R3;      // [16, 3, 65536]

    // ws: meanacc[48] | maxn[16] | pad->256B | cnt 2MB | off 2MB | cur 2MB |
    //     voxid 2MB(u16) | sortedvox 2MB(u16) | sortedfeat 134MB (bf16 rows)
    char* base = (char*)d_ws;
    float* meanacc = (float*)base;
    int*   maxn    = (int*)(base + 192);
    unsigned int*   cnt       = (unsigned int*)(base + 256);
    unsigned int*   off       = cnt + (size_t)NB * R3;
    unsigned int*   cur       = off + (size_t)NB * R3;
    unsigned short* voxid     = (unsigned short*)(cur + (size_t)NB * R3);
    unsigned short* sortedvox = voxid + (size_t)NB * NPTS;   // Path B reuses as point-id list
    const size_t sf_off = 256 + 3 * (size_t)NB * R3 * 4 + 2 * (size_t)NB * NPTS * 2;
    unsigned short* sortedfeat = (unsigned short*)(base + sf_off);
    const bool pathA = ws_size >= sf_off + (size_t)NB * NPTS * NC * sizeof(unsigned short);

    // cur region is dead after transpose_scatter: reuse for bcount + boundary list
    unsigned int* bcount = cur;
    unsigned int* blist  = cur + 64;

    // zero meanacc/maxn/cnt (~2 MB) and the grid accumulator (128 MB)
    hipMemsetAsync(d_ws, 0, 256 + (size_t)NB * R3 * sizeof(unsigned int), stream);
    hipMemsetAsync(d_out, 0, (size_t)NB * NC * R3 * sizeof(float), stream);

    mean_partial   <<<NB * 32, 256, 0, stream>>>(coords, meanacc);
    maxnorm_partial<<<NB * 32, 256, 0, stream>>>(coords, meanacc, maxn);
    voxelize       <<<NB * NPTS / 256, 256, 0, stream>>>(coords, meanacc, maxn, ncout, voxid, cnt);
    scan_kernel    <<<NB, 1024, 0, stream>>>(cnt, off, cur);
    if (pathA) {
        transpose_scatter<<<NB * (NPTS / 128), 256, 0, stream>>>(features, voxid, cur,
                                                                 sortedfeat, sortedvox);
        hipMemsetAsync(bcount, 0, sizeof(unsigned int), stream);   // cur dead now
        seg_reduce   <<<(NB * NPTS / 128) / 4, 256, 0, stream>>>(sortedfeat, sortedvox,
                                                                 off, cnt, grid, blist, bcount);
        fix_boundary <<<2048, 256, 0, stream>>>(blist, bcount, cnt, grid);
    } else {
        scatter_ids<<<NB * NPTS / 256, 256, 0, stream>>>(voxid, cur, sortedvox);
        gather_cpt8<<<(NB * 8) * (R3 / 256), 256, 0, stream>>>(features, sortedvox, off, cnt, grid);
    }
}